// Round 6
// baseline (87.303 us; speedup 1.0000x reference)
//
#include <hip/hip_runtime.h>
#include <hip/hip_bf16.h>

typedef __hip_bfloat16 bf16_t;
typedef __attribute__((ext_vector_type(4))) float f32x4;
typedef __attribute__((ext_vector_type(8))) __bf16 bf16x8;
typedef __attribute__((ext_vector_type(8))) short s16x8;
typedef __attribute__((ext_vector_type(4))) unsigned short u16x4;

#define BATCH 16384
#define NDIM  1024
#define HID   512
#define LAT   50

#define LOG2E 1.44269504088896340736f
#define RLOG2E 0.69314718055994530942f

// raw HW transcendentals (cdna4_isa §3): v_exp_f32 = 2^x, v_log_f32 = log2(x)
__device__ __forceinline__ float ex2(float x) { return __builtin_amdgcn_exp2f(x); }
__device__ __forceinline__ float lg2(float x) { return __builtin_amdgcn_logf(x); }
__device__ __forceinline__ float rcp(float x) { return __builtin_amdgcn_rcpf(x); }

__device__ inline unsigned short f2b_u(float f) {
  union { bf16_t b; unsigned short u; } cv; cv.b = __float2bfloat16(f); return cv.u;
}

// global -> LDS direct copy, 16B per lane. dst must be wave-uniform base;
// HW writes dst + lane*16 (guide §5).
__device__ __forceinline__ void gload16(const void* src, void* dst_lds) {
  __builtin_amdgcn_global_load_lds(
      reinterpret_cast<const __attribute__((address_space(1))) void*>(
          reinterpret_cast<unsigned long long>(src)),
      reinterpret_cast<__attribute__((address_space(3))) void*>(
          static_cast<unsigned>(reinterpret_cast<unsigned long long>(dst_lds))),
      16, 0, 0);
}

// ---------------------------------------------------------------------------
// prep: weights only. w1[512][1024], w3[1024][512] bf16; wab padded
// [128][512]; w2p padded [512][64]; bab[128] f32.
// ---------------------------------------------------------------------------
__global__ void prep_w_kernel(const float* __restrict__ W1, const float* __restrict__ W3,
                              const float* __restrict__ Wa, const float* __restrict__ Wb,
                              const float* __restrict__ W2, const float* __restrict__ ba,
                              const float* __restrict__ bb,
                              bf16_t* __restrict__ w1, bf16_t* __restrict__ w3,
                              bf16_t* __restrict__ wab, bf16_t* __restrict__ w2p,
                              float* __restrict__ bab)
{
  const int W1U  = (HID * NDIM) / 4;   // f32x4 units
  const int W3U  = (NDIM * HID) / 4;
  const int WABN = 128 * HID;
  const int W2PN = HID * 64;
  const int TOT  = W1U + W3U + WABN + W2PN + 128;
  for (int i = blockIdx.x * blockDim.x + threadIdx.x; i < TOT;
       i += gridDim.x * blockDim.x) {
    int j = i;
    if (j < W1U) {
      const f32x4 v = ((const f32x4*)W1)[j];
      u16x4 o; o[0]=f2b_u(v[0]); o[1]=f2b_u(v[1]); o[2]=f2b_u(v[2]); o[3]=f2b_u(v[3]);
      ((u16x4*)w1)[j] = o; continue;
    }
    j -= W1U;
    if (j < W3U) {
      const f32x4 v = ((const f32x4*)W3)[j];
      u16x4 o; o[0]=f2b_u(v[0]); o[1]=f2b_u(v[1]); o[2]=f2b_u(v[2]); o[3]=f2b_u(v[3]);
      ((u16x4*)w3)[j] = o; continue;
    }
    j -= W3U;
    if (j < WABN) {
      const int n = j >> 9, k = j & 511;
      float v = (n < 50) ? Wa[n * 512 + k] : ((n < 100) ? Wb[(n - 50) * 512 + k] : 0.f);
      wab[j] = __float2bfloat16(v); continue;
    }
    j -= WABN;
    if (j < W2PN) {
      const int n = j >> 6, k = j & 63;
      w2p[j] = __float2bfloat16(k < 50 ? W2[n * 50 + k] : 0.f); continue;
    }
    j -= W2PN;
    bab[j] = (j < 50) ? ba[j] : ((j < 100) ? bb[j - 50] : 0.f);
  }
}

// ---------------------------------------------------------------------------
// bf16 MFMA GEMM, C[M,N] = epi(A[M,K] @ B[N,K]^T + bias[N])
// Tile MT x 128, BK=64, 4 waves (2x2 of MT/2 x 64), mfma_f32_16x16x32_bf16.
// LDS tiles are bf16 [rows][8 slots of 16B], XOR-swizzled slot^(row&7):
//   B (and bf16 A): global_load_lds with PRE-SWIZZLED source (rule 21).
//   A_F32=1: A reg-staged — f32 load -> cvt ONCE -> swizzled ds_write_b128
//   (cvt off the ds_read->MFMA critical path; LDS stays bf16-sized).
// __launch_bounds__(256,4): 4 blocks/CU co-resident (24-32KB LDS, 68 VGPR)
// to hide the per-K-step vmcnt(0)+barrier drain (round-5 lesson).
// EPI: 0=relu->bf16, 1=sigmoid->f32, 2=softplus+1e-4 split alpha/beta->f32.
// XCD-bijective block swizzle (grids %8==0) + bn-fast order for L2 reuse.
// ---------------------------------------------------------------------------
template<int A_F32, int EPI, int MT>
__global__ __launch_bounds__(256, 4)
void gemm_kernel(const void* __restrict__ Av, const bf16_t* __restrict__ B,
                 const float* __restrict__ bias, void* __restrict__ out0,
                 float* __restrict__ out_a, float* __restrict__ out_b,
                 int M, int N, int K)
{
  constexpr int MI = MT / 32;                 // A frag count per wave
  __shared__ char lds[MT * 128 + 16384];      // A bf16 tile + B tile
  char* lA = lds;
  char* lB = lds + MT * 128;

  const int tid  = threadIdx.x;
  // XCD swizzle (T1, bijective since gridDim%8==0), bn-fast for A-panel reuse
  const int swzid = ((blockIdx.x & 7) * (gridDim.x >> 3)) + (blockIdx.x >> 3);
  const int nblocks = N >> 7;
  const int bn   = swzid % nblocks;
  const int bm   = swzid / nblocks;
  const int wid  = tid >> 6;
  const int lane = tid & 63;
  const int l15  = lane & 15;
  const int l4   = lane >> 4;
  const int wm   = (wid >> 1) * (MT / 2);
  const int wn   = (wid & 1) << 6;
  const int uw   = __builtin_amdgcn_readfirstlane(wid);

  f32x4 acc[MI][4] = {};

  for (int k0 = 0; k0 < K; k0 += 64) {
    // ---- B tile: 1024 16B cells via global_load_lds, pre-swizzled source
    #pragma unroll
    for (int i = 0; i < 4; ++i) {
      const int c  = (i * 4 + uw) * 64 + lane;    // cell this lane fills
      const int r  = c >> 3;
      const int sp = c & 7;                        // physical slot (linear dest)
      const int sl = sp ^ (r & 7);                 // logical slot to fetch
      gload16(B + (size_t)(bn * 128 + r) * K + k0 + sl * 8,
              lB + (i * 4 + uw) * 1024);
    }
    // ---- A tile (MT*8 cells of 8 bf16)
    if (A_F32) {
      const float* A = (const float*)Av;
      #pragma unroll
      for (int i = 0; i < MI; ++i) {
        const int c  = i * 256 + tid;
        const int r  = c >> 3;
        const int sl = c & 7;                      // logical slot
        const int sp = sl ^ (r & 7);               // physical (write-side swz)
        const float* s = A + (size_t)(bm * MT + r) * K + k0 + sl * 8;
        const f32x4 v0 = *(const f32x4*)s;
        const f32x4 v1 = *(const f32x4*)(s + 4);
        union { s16x8 v; unsigned short us[8]; } o;
        o.us[0]=f2b_u(v0[0]); o.us[1]=f2b_u(v0[1]); o.us[2]=f2b_u(v0[2]); o.us[3]=f2b_u(v0[3]);
        o.us[4]=f2b_u(v1[0]); o.us[5]=f2b_u(v1[1]); o.us[6]=f2b_u(v1[2]); o.us[7]=f2b_u(v1[3]);
        *(s16x8*)(lA + r * 128 + sp * 16) = o.v;
      }
    } else {
      const bf16_t* A = (const bf16_t*)Av;
      #pragma unroll
      for (int i = 0; i < MI; ++i) {
        const int c  = (i * 4 + uw) * 64 + lane;
        const int r  = c >> 3;
        const int sp = c & 7;
        const int sl = sp ^ (r & 7);
        gload16(A + (size_t)(bm * MT + r) * K + k0 + sl * 8,
                lA + (i * 4 + uw) * 1024);
      }
    }
    __syncthreads();

    #pragma unroll
    for (int h = 0; h < 2; ++h) {
      bf16x8 af[MI], bfr[4];
      #pragma unroll
      for (int mi = 0; mi < MI; ++mi) {
        const int row = wm + mi * 16 + l15;
        const int sp  = (h * 4 + l4) ^ (row & 7);
        af[mi] = *(const bf16x8*)(lA + row * 128 + sp * 16);
      }
      #pragma unroll
      for (int ni = 0; ni < 4; ++ni) {
        const int row = wn + ni * 16 + l15;
        const int sp  = (h * 4 + l4) ^ (row & 7);
        bfr[ni] = *(const bf16x8*)(lB + row * 128 + sp * 16);
      }
      #pragma unroll
      for (int mi = 0; mi < MI; ++mi)
        #pragma unroll
        for (int ni = 0; ni < 4; ++ni)
          acc[mi][ni] = __builtin_amdgcn_mfma_f32_16x16x32_bf16(
              af[mi], bfr[ni], acc[mi][ni], 0, 0, 0);
    }
    __syncthreads();
  }

  // ---- epilogue: C/D layout col=lane&15, row=(lane>>4)*4+reg (m89-verified)
  #pragma unroll
  for (int ni = 0; ni < 4; ++ni) {
    const int n  = bn * 128 + wn + ni * 16 + l15;
    const float bv = bias[n];
    #pragma unroll
    for (int mi = 0; mi < MI; ++mi) {
      #pragma unroll
      for (int r = 0; r < 4; ++r) {
        const int m  = bm * MT + wm + mi * 16 + l4 * 4 + r;
        const float t = acc[mi][ni][r] + bv;
        if (EPI == 2) {
          if (n < 100) {
            // softplus(t) = log2(1 + 2^(t*log2e)) / log2e
            const float y =
                (t > 20.f ? t : lg2(1.f + ex2(t * LOG2E)) * RLOG2E) + 1e-4f;
            if (n < 50) out_a[(size_t)m * 50 + n] = y;
            else        out_b[(size_t)m * 50 + (n - 50)] = y;
          }
        } else if (EPI == 0) {
          ((bf16_t*)out0)[(size_t)m * N + n] = __float2bfloat16(fmaxf(t, 0.f));
        } else {
          // sigmoid(t) = 1 / (1 + 2^(-t*log2e))
          ((float*)out0)[(size_t)m * N + n] = rcp(1.f + ex2(-t * LOG2E));
        }
      }
    }
  }
}

// ---------------------------------------------------------------------------
// stick-breaking: one wave per row (16384 waves -> full TLP). Raw v_log/v_exp
// for pow (err ~1e-6 vs 1.9e-2 threshold). 6-step shfl_up multiplicative
// scan for the exclusive cumprod. pi padded [B][64] bf16.
// ---------------------------------------------------------------------------
__global__ void stick_kernel(const float* __restrict__ u,
                             const float* __restrict__ alpha,
                             const float* __restrict__ beta,
                             bf16_t* __restrict__ pi)
{
  const int gw   = (blockIdx.x * blockDim.x + threadIdx.x) >> 6;
  const int lane = threadIdx.x & 63;
  if (gw >= BATCH) return;
  const size_t row = (size_t)gw;

  float v = 1.f, t = 1.f;
  if (lane < 49) {
    const float a  = alpha[row * 50 + lane];
    const float b  = beta[row * 50 + lane];
    const float uu = u[row * 50 + lane];
    const float tb = ex2(lg2(uu) * rcp(b));       // u^(1/b)
    v = ex2(lg2(1.f - tb) * rcp(a));              // (1-tb)^(1/a)
    t = 1.f - v;
  }
  // lane 49: v forced to 1 (set_v_K_to_one); lanes >=49 keep t=1 (benign)
  float p = t;
  #pragma unroll
  for (int d = 1; d < 64; d <<= 1) {
    const float o = __shfl_up(p, d, 64);
    if (lane >= d) p *= o;
  }
  float e = __shfl_up(p, 1, 64);
  if (lane == 0) e = 1.f;
  pi[row * 64 + lane] = __float2bfloat16(lane < 50 ? v * e : 0.f);
}

// ---------------------------------------------------------------------------
extern "C" void kernel_launch(void* const* d_in, const int* in_sizes, int n_in,
                              void* d_out, int out_size, void* d_ws, size_t ws_size,
                              hipStream_t stream)
{
  const float* x  = (const float*)d_in[0];
  const float* u  = (const float*)d_in[1];
  const float* W1 = (const float*)d_in[2];
  const float* b1 = (const float*)d_in[3];
  const float* Wa = (const float*)d_in[4];
  const float* ba = (const float*)d_in[5];
  const float* Wb = (const float*)d_in[6];
  const float* bb = (const float*)d_in[7];
  const float* W2 = (const float*)d_in[8];
  const float* b2 = (const float*)d_in[9];
  const float* W3 = (const float*)d_in[10];
  const float* b3 = (const float*)d_in[11];

  float* recon  = (float*)d_out;
  float* oalpha = recon + (size_t)BATCH * NDIM;
  float* obeta  = oalpha + (size_t)BATCH * LAT;

  // ws layout (16B-aligned offsets), total 37,945,856 B
  char* ws = (char*)d_ws;
  bf16_t* h   = (bf16_t*)(ws);                 // 16,777,216
  bf16_t* h2  = (bf16_t*)(ws + 16777216);      // 16,777,216
  bf16_t* pi  = (bf16_t*)(ws + 33554432);      //  2,097,152
  bf16_t* w1  = (bf16_t*)(ws + 35651584);      //  1,048,576
  bf16_t* w3  = (bf16_t*)(ws + 36700160);      //  1,048,576
  bf16_t* wab = (bf16_t*)(ws + 37748736);      //    131,072
  bf16_t* w2p = (bf16_t*)(ws + 37879808);      //     65,536
  float*  bab = (float*)(ws + 37945344);       //        512

  prep_w_kernel<<<512, 256, 0, stream>>>(W1, W3, Wa, Wb, W2, ba, bb,
                                         w1, w3, wab, w2p, bab);
  // h = relu(x @ W1^T + b1); A=x f32 reg-staged; MT=64 -> 1024 blocks (4/CU)
  gemm_kernel<1, 0, 64><<<1024, 256, 0, stream>>>(
      x, w1, b1, (void*)h, nullptr, nullptr, BATCH, HID, NDIM);
  // alpha/beta = softplus(h @ Wab^T + bab)+1e-4 -> d_out  (MT=64: 256 blocks)
  gemm_kernel<0, 2, 64><<<256, 256, 0, stream>>>(
      h, wab, bab, nullptr, oalpha, obeta, BATCH, 128, HID);
  // pi (stick-breaking) -> ws, padded [16384,64] bf16
  stick_kernel<<<4096, 256, 0, stream>>>(u, oalpha, obeta, pi);
  // h2 = relu(pi @ W2p^T + b2)  (MT=64: 1024 blocks)
  gemm_kernel<0, 0, 64><<<1024, 256, 0, stream>>>(
      pi, w2p, b2, (void*)h2, nullptr, nullptr, BATCH, HID, 64);
  // recon = sigmoid(h2 @ W3^T + b3)  (MT=128: 1024 blocks)
  gemm_kernel<0, 1, 128><<<1024, 256, 0, stream>>>(
      h2, w3, b3, (void*)recon, nullptr, nullptr, BATCH, NDIM, HID);
}

// Round 7
// 86.072 us; speedup vs baseline: 1.0143x; 1.0143x over previous
//
#include <hip/hip_runtime.h>
#include <hip/hip_bf16.h>

typedef __hip_bfloat16 bf16_t;
typedef __attribute__((ext_vector_type(4))) float f32x4;
typedef __attribute__((ext_vector_type(8))) __bf16 bf16x8;
typedef __attribute__((ext_vector_type(8))) short s16x8;
typedef __attribute__((ext_vector_type(4))) unsigned short u16x4;

#define BATCH 16384
#define NDIM  1024
#define HID   512
#define LAT   50

#define LOG2E 1.44269504088896340736f
#define RLOG2E 0.69314718055994530942f

// raw HW transcendentals (cdna4_isa §3): v_exp_f32 = 2^x, v_log_f32 = log2(x)
__device__ __forceinline__ float ex2(float x) { return __builtin_amdgcn_exp2f(x); }
__device__ __forceinline__ float lg2(float x) { return __builtin_amdgcn_logf(x); }
__device__ __forceinline__ float rcp(float x) { return __builtin_amdgcn_rcpf(x); }

__device__ inline unsigned short f2b_u(float f) {
  union { bf16_t b; unsigned short u; } cv; cv.b = __float2bfloat16(f); return cv.u;
}

// global -> LDS direct copy, 16B per lane. dst must be wave-uniform base;
// HW writes dst + lane*16 (guide §5).
__device__ __forceinline__ void gload16(const void* src, void* dst_lds) {
  __builtin_amdgcn_global_load_lds(
      reinterpret_cast<const __attribute__((address_space(1))) void*>(
          reinterpret_cast<unsigned long long>(src)),
      reinterpret_cast<__attribute__((address_space(3))) void*>(
          static_cast<unsigned>(reinterpret_cast<unsigned long long>(dst_lds))),
      16, 0, 0);
}

// ---------------------------------------------------------------------------
// prep: weights only. w1[512][1024], w3[1024][512] bf16; wab padded
// [128][512]; w2p padded [512][64]; bab[128] f32.
// ---------------------------------------------------------------------------
__global__ void prep_w_kernel(const float* __restrict__ W1, const float* __restrict__ W3,
                              const float* __restrict__ Wa, const float* __restrict__ Wb,
                              const float* __restrict__ W2, const float* __restrict__ ba,
                              const float* __restrict__ bb,
                              bf16_t* __restrict__ w1, bf16_t* __restrict__ w3,
                              bf16_t* __restrict__ wab, bf16_t* __restrict__ w2p,
                              float* __restrict__ bab)
{
  const int W1U  = (HID * NDIM) / 4;   // f32x4 units
  const int W3U  = (NDIM * HID) / 4;
  const int WABN = 128 * HID;
  const int W2PN = HID * 64;
  const int TOT  = W1U + W3U + WABN + W2PN + 128;
  for (int i = blockIdx.x * blockDim.x + threadIdx.x; i < TOT;
       i += gridDim.x * blockDim.x) {
    int j = i;
    if (j < W1U) {
      const f32x4 v = ((const f32x4*)W1)[j];
      u16x4 o; o[0]=f2b_u(v[0]); o[1]=f2b_u(v[1]); o[2]=f2b_u(v[2]); o[3]=f2b_u(v[3]);
      ((u16x4*)w1)[j] = o; continue;
    }
    j -= W1U;
    if (j < W3U) {
      const f32x4 v = ((const f32x4*)W3)[j];
      u16x4 o; o[0]=f2b_u(v[0]); o[1]=f2b_u(v[1]); o[2]=f2b_u(v[2]); o[3]=f2b_u(v[3]);
      ((u16x4*)w3)[j] = o; continue;
    }
    j -= W3U;
    if (j < WABN) {
      const int n = j >> 9, k = j & 511;
      float v = (n < 50) ? Wa[n * 512 + k] : ((n < 100) ? Wb[(n - 50) * 512 + k] : 0.f);
      wab[j] = __float2bfloat16(v); continue;
    }
    j -= WABN;
    if (j < W2PN) {
      const int n = j >> 6, k = j & 63;
      w2p[j] = __float2bfloat16(k < 50 ? W2[n * 50 + k] : 0.f); continue;
    }
    j -= W2PN;
    bab[j] = (j < 50) ? ba[j] : ((j < 100) ? bb[j - 50] : 0.f);
  }
}

// ---------------------------------------------------------------------------
// bf16 MFMA GEMM, C[M,N] = epi(A[M,K] @ B[N,K]^T + bias[N])
// Tile MT x 128, BK=64, 4 waves (2x2 of MT/2 x 64), mfma_f32_16x16x32_bf16.
// LDS tiles bf16 [rows][8 slots of 16B], XOR-swizzled slot^(row&7):
//   B (and bf16 A): global_load_lds, PRE-SWIZZLED source (rule 21).
//   A_F32=1: A reg-staged, T14 split (issue loads -> compute -> cvt+ds_write).
// DB=1: 2-phase double-buffer K-loop (T3 minimum recipe) — stage tile t+1
//   into buf^1 BEFORE computing buf, ONE __syncthreads per K-step. Safe:
//   each wave's ds_reads complete before its MFMAs (compiler lgkmcnt),
//   hence before the barrier; post-barrier overwrite cannot race.
// DB=0: single-buffer, only valid for nt==1 (K<=64).
// EPI: 0=relu->bf16, 1=sigmoid->f32, 2=softplus+1e-4 split alpha/beta->f32.
// XCD-bijective block swizzle (grids %8==0) + bn-fast order for L2 reuse.
// ---------------------------------------------------------------------------
template<int A_F32, int EPI, int MT, int DB>
__global__ __launch_bounds__(256, DB ? (MT == 128 ? 2 : 3) : 4)
void gemm_kernel(const void* __restrict__ Av, const bf16_t* __restrict__ B,
                 const float* __restrict__ bias, void* __restrict__ out0,
                 float* __restrict__ out_a, float* __restrict__ out_b,
                 int M, int N, int K)
{
  constexpr int MI  = MT / 32;                // A frag count per wave
  constexpr int BUF = MT * 128 + 16384;       // A bf16 tile + B tile
  __shared__ char lds[(DB ? 2 : 1) * BUF];

  const int tid  = threadIdx.x;
  // XCD swizzle (T1, bijective since gridDim%8==0), bn-fast for A-panel reuse
  const int swzid = ((blockIdx.x & 7) * (gridDim.x >> 3)) + (blockIdx.x >> 3);
  const int nblocks = N >> 7;
  const int bn   = swzid % nblocks;
  const int bm   = swzid / nblocks;
  const int wid  = tid >> 6;
  const int lane = tid & 63;
  const int l15  = lane & 15;
  const int l4   = lane >> 4;
  const int wm   = (wid >> 1) * (MT / 2);
  const int wn   = (wid & 1) << 6;
  const int uw   = __builtin_amdgcn_readfirstlane(wid);

  f32x4 acc[MI][4] = {};
  f32x4 areg[2 * MI];                          // A_F32 in-flight tile regs

  // ---- staging helpers -----------------------------------------------------
  auto stage_B = [&](char* buf, int k0) {
    char* lB = buf + MT * 128;
    #pragma unroll
    for (int i = 0; i < 4; ++i) {
      const int c  = (i * 4 + uw) * 64 + lane;  // cell this lane fills
      const int r  = c >> 3;
      const int sp = c & 7;                     // physical slot (linear dest)
      const int sl = sp ^ (r & 7);              // logical slot to fetch
      gload16(B + (size_t)(bn * 128 + r) * K + k0 + sl * 8,
              lB + (i * 4 + uw) * 1024);
    }
  };
  auto stage_A_bf16 = [&](char* buf, int k0) {
    const bf16_t* A = (const bf16_t*)Av;
    #pragma unroll
    for (int i = 0; i < MI; ++i) {
      const int c  = (i * 4 + uw) * 64 + lane;
      const int r  = c >> 3;
      const int sp = c & 7;
      const int sl = sp ^ (r & 7);
      gload16(A + (size_t)(bm * MT + r) * K + k0 + sl * 8,
              buf + (i * 4 + uw) * 1024);
    }
  };
  auto load_A_f32 = [&](int k0) {              // T14: issue loads only
    const float* A = (const float*)Av;
    #pragma unroll
    for (int i = 0; i < MI; ++i) {
      const int c  = i * 256 + tid;
      const int r  = c >> 3;
      const int sl = c & 7;
      const float* s = A + (size_t)(bm * MT + r) * K + k0 + sl * 8;
      areg[2 * i]     = *(const f32x4*)s;
      areg[2 * i + 1] = *(const f32x4*)(s + 4);
    }
  };
  auto write_A_f32 = [&](char* buf) {          // T14: cvt + ds_write late
    #pragma unroll
    for (int i = 0; i < MI; ++i) {
      const int c  = i * 256 + tid;
      const int r  = c >> 3;
      const int sl = c & 7;
      const int sp = sl ^ (r & 7);
      union { s16x8 v; unsigned short us[8]; } o;
      const f32x4 v0 = areg[2 * i], v1 = areg[2 * i + 1];
      o.us[0]=f2b_u(v0[0]); o.us[1]=f2b_u(v0[1]); o.us[2]=f2b_u(v0[2]); o.us[3]=f2b_u(v0[3]);
      o.us[4]=f2b_u(v1[0]); o.us[5]=f2b_u(v1[1]); o.us[6]=f2b_u(v1[2]); o.us[7]=f2b_u(v1[3]);
      *(s16x8*)(buf + r * 128 + sp * 16) = o.v;
    }
  };
  auto compute = [&](const char* buf) {
    const char* lA = buf;
    const char* lB = buf + MT * 128;
    #pragma unroll
    for (int h = 0; h < 2; ++h) {
      bf16x8 af[MI], bfr[4];
      #pragma unroll
      for (int mi = 0; mi < MI; ++mi) {
        const int row = wm + mi * 16 + l15;
        const int sp  = (h * 4 + l4) ^ (row & 7);
        af[mi] = *(const bf16x8*)(lA + row * 128 + sp * 16);
      }
      #pragma unroll
      for (int ni = 0; ni < 4; ++ni) {
        const int row = wn + ni * 16 + l15;
        const int sp  = (h * 4 + l4) ^ (row & 7);
        bfr[ni] = *(const bf16x8*)(lB + row * 128 + sp * 16);
      }
      #pragma unroll
      for (int mi = 0; mi < MI; ++mi)
        #pragma unroll
        for (int ni = 0; ni < 4; ++ni)
          acc[mi][ni] = __builtin_amdgcn_mfma_f32_16x16x32_bf16(
              af[mi], bfr[ni], acc[mi][ni], 0, 0, 0);
    }
  };

  // ---- 2-phase double-buffered K-loop (T3 minimum) -------------------------
  const int nt = K >> 6;
  // prologue: stage tile 0 into buf0
  if (A_F32) { load_A_f32(0); write_A_f32(lds); }
  else       { stage_A_bf16(lds, 0); }
  stage_B(lds, 0);
  __syncthreads();

  int cur = 0;
  for (int t = 0; t < nt - 1; ++t) {
    char* nbuf = lds + (DB ? (cur ^ 1) * BUF : 0);
    const int k0n = (t + 1) << 6;
    if (A_F32) load_A_f32(k0n);          // issue early (T14)
    else       stage_A_bf16(nbuf, k0n);  // async direct-to-LDS
    stage_B(nbuf, k0n);                  // async direct-to-LDS
    compute(lds + cur * BUF);            // overlaps the loads above
    if (A_F32) write_A_f32(nbuf);        // vmcnt wait lands here, post-MFMA
    __syncthreads();                     // drain stage; buffers flip
    cur ^= 1;
  }
  compute(lds + cur * BUF);

  // ---- epilogue: C/D layout col=lane&15, row=(lane>>4)*4+reg (m89-verified)
  #pragma unroll
  for (int ni = 0; ni < 4; ++ni) {
    const int n  = bn * 128 + wn + ni * 16 + l15;
    const float bv = bias[n];
    #pragma unroll
    for (int mi = 0; mi < MI; ++mi) {
      #pragma unroll
      for (int r = 0; r < 4; ++r) {
        const int m  = bm * MT + wm + mi * 16 + l4 * 4 + r;
        const float t = acc[mi][ni][r] + bv;
        if (EPI == 2) {
          if (n < 100) {
            // softplus(t) = log2(1 + 2^(t*log2e)) / log2e
            const float y =
                (t > 20.f ? t : lg2(1.f + ex2(t * LOG2E)) * RLOG2E) + 1e-4f;
            if (n < 50) out_a[(size_t)m * 50 + n] = y;
            else        out_b[(size_t)m * 50 + (n - 50)] = y;
          }
        } else if (EPI == 0) {
          ((bf16_t*)out0)[(size_t)m * N + n] = __float2bfloat16(fmaxf(t, 0.f));
        } else {
          // sigmoid(t) = 1 / (1 + 2^(-t*log2e))
          ((float*)out0)[(size_t)m * N + n] = rcp(1.f + ex2(-t * LOG2E));
        }
      }
    }
  }
}

// ---------------------------------------------------------------------------
// stick-breaking: one wave per row (16384 waves -> full TLP). Raw v_log/v_exp
// for pow (err ~1e-6 vs 1.9e-2 threshold). 6-step shfl_up multiplicative
// scan for the exclusive cumprod. pi padded [B][64] bf16.
// ---------------------------------------------------------------------------
__global__ void stick_kernel(const float* __restrict__ u,
                             const float* __restrict__ alpha,
                             const float* __restrict__ beta,
                             bf16_t* __restrict__ pi)
{
  const int gw   = (blockIdx.x * blockDim.x + threadIdx.x) >> 6;
  const int lane = threadIdx.x & 63;
  if (gw >= BATCH) return;
  const size_t row = (size_t)gw;

  float v = 1.f, t = 1.f;
  if (lane < 49) {
    const float a  = alpha[row * 50 + lane];
    const float b  = beta[row * 50 + lane];
    const float uu = u[row * 50 + lane];
    const float tb = ex2(lg2(uu) * rcp(b));       // u^(1/b)
    v = ex2(lg2(1.f - tb) * rcp(a));              // (1-tb)^(1/a)
    t = 1.f - v;
  }
  // lane 49: v forced to 1 (set_v_K_to_one); lanes >=49 keep t=1 (benign)
  float p = t;
  #pragma unroll
  for (int d = 1; d < 64; d <<= 1) {
    const float o = __shfl_up(p, d, 64);
    if (lane >= d) p *= o;
  }
  float e = __shfl_up(p, 1, 64);
  if (lane == 0) e = 1.f;
  pi[row * 64 + lane] = __float2bfloat16(lane < 50 ? v * e : 0.f);
}

// ---------------------------------------------------------------------------
extern "C" void kernel_launch(void* const* d_in, const int* in_sizes, int n_in,
                              void* d_out, int out_size, void* d_ws, size_t ws_size,
                              hipStream_t stream)
{
  const float* x  = (const float*)d_in[0];
  const float* u  = (const float*)d_in[1];
  const float* W1 = (const float*)d_in[2];
  const float* b1 = (const float*)d_in[3];
  const float* Wa = (const float*)d_in[4];
  const float* ba = (const float*)d_in[5];
  const float* Wb = (const float*)d_in[6];
  const float* bb = (const float*)d_in[7];
  const float* W2 = (const float*)d_in[8];
  const float* b2 = (const float*)d_in[9];
  const float* W3 = (const float*)d_in[10];
  const float* b3 = (const float*)d_in[11];

  float* recon  = (float*)d_out;
  float* oalpha = recon + (size_t)BATCH * NDIM;
  float* obeta  = oalpha + (size_t)BATCH * LAT;

  // ws layout (16B-aligned offsets), total 37,945,856 B
  char* ws = (char*)d_ws;
  bf16_t* h   = (bf16_t*)(ws);                 // 16,777,216
  bf16_t* h2  = (bf16_t*)(ws + 16777216);      // 16,777,216
  bf16_t* pi  = (bf16_t*)(ws + 33554432);      //  2,097,152
  bf16_t* w1  = (bf16_t*)(ws + 35651584);      //  1,048,576
  bf16_t* w3  = (bf16_t*)(ws + 36700160);      //  1,048,576
  bf16_t* wab = (bf16_t*)(ws + 37748736);      //    131,072
  bf16_t* w2p = (bf16_t*)(ws + 37879808);      //     65,536
  float*  bab = (float*)(ws + 37945344);       //        512

  prep_w_kernel<<<512, 256, 0, stream>>>(W1, W3, Wa, Wb, W2, ba, bb,
                                         w1, w3, wab, w2p, bab);
  // h = relu(x @ W1^T + b1); MT=128, dbuf, A=x f32 reg-staged (T14 split)
  gemm_kernel<1, 0, 128, 1><<<512, 256, 0, stream>>>(
      x, w1, b1, (void*)h, nullptr, nullptr, BATCH, HID, NDIM);
  // alpha/beta = softplus(h @ Wab^T + bab)+1e-4 -> d_out  (MT=64, dbuf)
  gemm_kernel<0, 2, 64, 1><<<256, 256, 0, stream>>>(
      h, wab, bab, nullptr, oalpha, obeta, BATCH, 128, HID);
  // pi (stick-breaking) -> ws, padded [16384,64] bf16
  stick_kernel<<<4096, 256, 0, stream>>>(u, oalpha, obeta, pi);
  // h2 = relu(pi @ W2p^T + b2)  (MT=64, K=64 -> nt=1, single-buffer)
  gemm_kernel<0, 0, 64, 0><<<1024, 256, 0, stream>>>(
      pi, w2p, b2, (void*)h2, nullptr, nullptr, BATCH, HID, 64);
  // recon = sigmoid(h2 @ W3^T + b3)  (MT=128, dbuf)
  gemm_kernel<0, 1, 128, 1><<<1024, 256, 0, stream>>>(
      h2, w3, b3, (void*)recon, nullptr, nullptr, BATCH, NDIM, HID);
}

// Round 8
// 85.155 us; speedup vs baseline: 1.0252x; 1.0108x over previous
//
#include <hip/hip_runtime.h>
#include <hip/hip_bf16.h>

typedef __hip_bfloat16 bf16_t;
typedef __attribute__((ext_vector_type(4))) float f32x4;
typedef __attribute__((ext_vector_type(8))) __bf16 bf16x8;
typedef __attribute__((ext_vector_type(8))) short s16x8;
typedef __attribute__((ext_vector_type(4))) unsigned short u16x4;

#define BATCH 16384
#define NDIM  1024
#define HID   512
#define LAT   50

#define LOG2E 1.44269504088896340736f
#define RLOG2E 0.69314718055994530942f

// raw HW transcendentals (cdna4_isa §3): v_exp_f32 = 2^x, v_log_f32 = log2(x)
__device__ __forceinline__ float ex2(float x) { return __builtin_amdgcn_exp2f(x); }
__device__ __forceinline__ float lg2(float x) { return __builtin_amdgcn_logf(x); }
__device__ __forceinline__ float rcp(float x) { return __builtin_amdgcn_rcpf(x); }

__device__ inline unsigned short f2b_u(float f) {
  union { bf16_t b; unsigned short u; } cv; cv.b = __float2bfloat16(f); return cv.u;
}

// global -> LDS direct copy, 16B per lane. dst must be wave-uniform base;
// HW writes dst + lane*16 (guide §5).
__device__ __forceinline__ void gload16(const void* src, void* dst_lds) {
  __builtin_amdgcn_global_load_lds(
      reinterpret_cast<const __attribute__((address_space(1))) void*>(
          reinterpret_cast<unsigned long long>(src)),
      reinterpret_cast<__attribute__((address_space(3))) void*>(
          static_cast<unsigned>(reinterpret_cast<unsigned long long>(dst_lds))),
      16, 0, 0);
}

// ---------------------------------------------------------------------------
// prep: weights only. w1[512][1024], w3[1024][512] bf16; wab padded
// [128][512]; w2p padded [512][64]; bab[128] f32.
// ---------------------------------------------------------------------------
__global__ void prep_w_kernel(const float* __restrict__ W1, const float* __restrict__ W3,
                              const float* __restrict__ Wa, const float* __restrict__ Wb,
                              const float* __restrict__ W2, const float* __restrict__ ba,
                              const float* __restrict__ bb,
                              bf16_t* __restrict__ w1, bf16_t* __restrict__ w3,
                              bf16_t* __restrict__ wab, bf16_t* __restrict__ w2p,
                              float* __restrict__ bab)
{
  const int W1U  = (HID * NDIM) / 4;   // f32x4 units
  const int W3U  = (NDIM * HID) / 4;
  const int WABN = 128 * HID;
  const int W2PN = HID * 64;
  const int TOT  = W1U + W3U + WABN + W2PN + 128;
  for (int i = blockIdx.x * blockDim.x + threadIdx.x; i < TOT;
       i += gridDim.x * blockDim.x) {
    int j = i;
    if (j < W1U) {
      const f32x4 v = ((const f32x4*)W1)[j];
      u16x4 o; o[0]=f2b_u(v[0]); o[1]=f2b_u(v[1]); o[2]=f2b_u(v[2]); o[3]=f2b_u(v[3]);
      ((u16x4*)w1)[j] = o; continue;
    }
    j -= W1U;
    if (j < W3U) {
      const f32x4 v = ((const f32x4*)W3)[j];
      u16x4 o; o[0]=f2b_u(v[0]); o[1]=f2b_u(v[1]); o[2]=f2b_u(v[2]); o[3]=f2b_u(v[3]);
      ((u16x4*)w3)[j] = o; continue;
    }
    j -= W3U;
    if (j < WABN) {
      const int n = j >> 9, k = j & 511;
      float v = (n < 50) ? Wa[n * 512 + k] : ((n < 100) ? Wb[(n - 50) * 512 + k] : 0.f);
      wab[j] = __float2bfloat16(v); continue;
    }
    j -= WABN;
    if (j < W2PN) {
      const int n = j >> 6, k = j & 63;
      w2p[j] = __float2bfloat16(k < 50 ? W2[n * 50 + k] : 0.f); continue;
    }
    j -= W2PN;
    bab[j] = (j < 50) ? ba[j] : ((j < 100) ? bb[j - 50] : 0.f);
  }
}

// ---------------------------------------------------------------------------
// bf16 MFMA GEMM, C[M,N] = epi(A[M,K] @ B[N,K]^T + bias[N])
// Tile MT x 128, BK=64, **8 waves (512 thr), 2M x 4N**, per-wave MT/2 x 32,
// mfma_f32_16x16x32_bf16. 4 waves/SIMD at 2 blocks/CU (round-7 lesson:
// 2 waves/SIMD cannot hide the staging latency; double the TLP).
// LDS tiles bf16 [rows][8 slots of 16B], XOR-swizzled slot^(row&7):
//   B (and bf16 A): global_load_lds, PRE-SWIZZLED source (rule 21).
//   A_F32=1: A reg-staged, T14 split (issue loads -> compute -> cvt+ds_write).
// DB=1: 2-phase double-buffer K-loop, one __syncthreads per K-step.
// EPI: 0=relu->bf16, 1=sigmoid->f32, 2=softplus+1e-4 split alpha/beta->f32.
// XCD-bijective block swizzle (grids %8==0) + bn-fast order for L2 reuse.
// ---------------------------------------------------------------------------
template<int A_F32, int EPI, int MT, int DB>
__global__ __launch_bounds__(512, 4)
void gemm_kernel(const void* __restrict__ Av, const bf16_t* __restrict__ B,
                 const float* __restrict__ bias, void* __restrict__ out0,
                 float* __restrict__ out_a, float* __restrict__ out_b,
                 int M, int N, int K)
{
  constexpr int MI  = MT / 32;                // A frags per wave (rows/16)
  constexpr int IA  = MT / 64;                // A staging iters per thread
  constexpr int BUF = MT * 128 + 16384;       // A bf16 tile + B tile
  __shared__ char lds[(DB ? 2 : 1) * BUF];

  const int tid  = threadIdx.x;
  // XCD swizzle (T1, bijective since gridDim%8==0), bn-fast for A-panel reuse
  const int swzid = ((blockIdx.x & 7) * (gridDim.x >> 3)) + (blockIdx.x >> 3);
  const int nblocks = N >> 7;
  const int bn   = swzid % nblocks;
  const int bm   = swzid / nblocks;
  const int wid  = tid >> 6;
  const int lane = tid & 63;
  const int l15  = lane & 15;
  const int l4   = lane >> 4;
  const int wm   = (wid >> 2) * (MT / 2);     // 2 wave-rows
  const int wn   = (wid & 3) << 5;            // 4 wave-cols of 32
  const int uw   = __builtin_amdgcn_readfirstlane(wid);

  f32x4 acc[MI][2] = {};
  f32x4 areg[2 * IA];                          // A_F32 in-flight tile regs

  // ---- staging helpers -----------------------------------------------------
  auto stage_B = [&](char* buf, int k0) {
    char* lB = buf + MT * 128;
    #pragma unroll
    for (int i = 0; i < 2; ++i) {
      const int c  = (i * 8 + uw) * 64 + lane;  // cell this lane fills
      const int r  = c >> 3;
      const int sp = c & 7;                     // physical slot (linear dest)
      const int sl = sp ^ (r & 7);              // logical slot to fetch
      gload16(B + (size_t)(bn * 128 + r) * K + k0 + sl * 8,
              lB + (i * 8 + uw) * 1024);
    }
  };
  auto stage_A_bf16 = [&](char* buf, int k0) {
    const bf16_t* A = (const bf16_t*)Av;
    #pragma unroll
    for (int i = 0; i < IA; ++i) {
      const int c  = (i * 8 + uw) * 64 + lane;
      const int r  = c >> 3;
      const int sp = c & 7;
      const int sl = sp ^ (r & 7);
      gload16(A + (size_t)(bm * MT + r) * K + k0 + sl * 8,
              buf + (i * 8 + uw) * 1024);
    }
  };
  auto load_A_f32 = [&](int k0) {              // T14: issue loads only
    const float* A = (const float*)Av;
    #pragma unroll
    for (int i = 0; i < IA; ++i) {
      const int c  = i * 512 + tid;
      const int r  = c >> 3;
      const int sl = c & 7;
      const float* s = A + (size_t)(bm * MT + r) * K + k0 + sl * 8;
      areg[2 * i]     = *(const f32x4*)s;
      areg[2 * i + 1] = *(const f32x4*)(s + 4);
    }
  };
  auto write_A_f32 = [&](char* buf) {          // T14: cvt + ds_write late
    #pragma unroll
    for (int i = 0; i < IA; ++i) {
      const int c  = i * 512 + tid;
      const int r  = c >> 3;
      const int sl = c & 7;
      const int sp = sl ^ (r & 7);
      union { s16x8 v; unsigned short us[8]; } o;
      const f32x4 v0 = areg[2 * i], v1 = areg[2 * i + 1];
      o.us[0]=f2b_u(v0[0]); o.us[1]=f2b_u(v0[1]); o.us[2]=f2b_u(v0[2]); o.us[3]=f2b_u(v0[3]);
      o.us[4]=f2b_u(v1[0]); o.us[5]=f2b_u(v1[1]); o.us[6]=f2b_u(v1[2]); o.us[7]=f2b_u(v1[3]);
      *(s16x8*)(buf + r * 128 + sp * 16) = o.v;
    }
  };
  auto compute = [&](const char* buf) {
    const char* lA = buf;
    const char* lB = buf + MT * 128;
    #pragma unroll
    for (int h = 0; h < 2; ++h) {
      bf16x8 af[MI], bfr[2];
      #pragma unroll
      for (int mi = 0; mi < MI; ++mi) {
        const int row = wm + mi * 16 + l15;
        const int sp  = (h * 4 + l4) ^ (row & 7);
        af[mi] = *(const bf16x8*)(lA + row * 128 + sp * 16);
      }
      #pragma unroll
      for (int ni = 0; ni < 2; ++ni) {
        const int row = wn + ni * 16 + l15;
        const int sp  = (h * 4 + l4) ^ (row & 7);
        bfr[ni] = *(const bf16x8*)(lB + row * 128 + sp * 16);
      }
      #pragma unroll
      for (int mi = 0; mi < MI; ++mi)
        #pragma unroll
        for (int ni = 0; ni < 2; ++ni)
          acc[mi][ni] = __builtin_amdgcn_mfma_f32_16x16x32_bf16(
              af[mi], bfr[ni], acc[mi][ni], 0, 0, 0);
    }
  };

  // ---- 2-phase double-buffered K-loop --------------------------------------
  const int nt = K >> 6;
  if (A_F32) { load_A_f32(0); write_A_f32(lds); }
  else       { stage_A_bf16(lds, 0); }
  stage_B(lds, 0);
  __syncthreads();

  int cur = 0;
  for (int t = 0; t < nt - 1; ++t) {
    char* nbuf = lds + (DB ? (cur ^ 1) * BUF : 0);
    const int k0n = (t + 1) << 6;
    if (A_F32) load_A_f32(k0n);          // issue early (T14)
    else       stage_A_bf16(nbuf, k0n);  // async direct-to-LDS
    stage_B(nbuf, k0n);                  // async direct-to-LDS
    compute(lds + cur * BUF);            // overlaps the loads above
    if (A_F32) write_A_f32(nbuf);        // vmcnt wait lands here, post-MFMA
    __syncthreads();                     // drain stage; buffers flip
    cur ^= 1;
  }
  compute(lds + cur * BUF);

  // ---- epilogue: C/D layout col=lane&15, row=(lane>>4)*4+reg (m89-verified)
  #pragma unroll
  for (int ni = 0; ni < 2; ++ni) {
    const int n  = bn * 128 + wn + ni * 16 + l15;
    const float bv = bias[n];
    #pragma unroll
    for (int mi = 0; mi < MI; ++mi) {
      #pragma unroll
      for (int r = 0; r < 4; ++r) {
        const int m  = bm * MT + wm + mi * 16 + l4 * 4 + r;
        const float t = acc[mi][ni][r] + bv;
        if (EPI == 2) {
          if (n < 100) {
            // softplus(t) = log2(1 + 2^(t*log2e)) / log2e
            const float y =
                (t > 20.f ? t : lg2(1.f + ex2(t * LOG2E)) * RLOG2E) + 1e-4f;
            if (n < 50) out_a[(size_t)m * 50 + n] = y;
            else        out_b[(size_t)m * 50 + (n - 50)] = y;
          }
        } else if (EPI == 0) {
          ((bf16_t*)out0)[(size_t)m * N + n] = __float2bfloat16(fmaxf(t, 0.f));
        } else {
          // sigmoid(t) = 1 / (1 + 2^(-t*log2e))
          ((float*)out0)[(size_t)m * N + n] = rcp(1.f + ex2(-t * LOG2E));
        }
      }
    }
  }
}

// ---------------------------------------------------------------------------
// stick-breaking: one wave per row (16384 waves -> full TLP). Raw v_log/v_exp
// for pow (err ~1e-6 vs 1.9e-2 threshold). 6-step shfl_up multiplicative
// scan for the exclusive cumprod. pi padded [B][64] bf16.
// ---------------------------------------------------------------------------
__global__ void stick_kernel(const float* __restrict__ u,
                             const float* __restrict__ alpha,
                             const float* __restrict__ beta,
                             bf16_t* __restrict__ pi)
{
  const int gw   = (blockIdx.x * blockDim.x + threadIdx.x) >> 6;
  const int lane = threadIdx.x & 63;
  if (gw >= BATCH) return;
  const size_t row = (size_t)gw;

  float v = 1.f, t = 1.f;
  if (lane < 49) {
    const float a  = alpha[row * 50 + lane];
    const float b  = beta[row * 50 + lane];
    const float uu = u[row * 50 + lane];
    const float tb = ex2(lg2(uu) * rcp(b));       // u^(1/b)
    v = ex2(lg2(1.f - tb) * rcp(a));              // (1-tb)^(1/a)
    t = 1.f - v;
  }
  // lane 49: v forced to 1 (set_v_K_to_one); lanes >=49 keep t=1 (benign)
  float p = t;
  #pragma unroll
  for (int d = 1; d < 64; d <<= 1) {
    const float o = __shfl_up(p, d, 64);
    if (lane >= d) p *= o;
  }
  float e = __shfl_up(p, 1, 64);
  if (lane == 0) e = 1.f;
  pi[row * 64 + lane] = __float2bfloat16(lane < 50 ? v * e : 0.f);
}

// ---------------------------------------------------------------------------
extern "C" void kernel_launch(void* const* d_in, const int* in_sizes, int n_in,
                              void* d_out, int out_size, void* d_ws, size_t ws_size,
                              hipStream_t stream)
{
  const float* x  = (const float*)d_in[0];
  const float* u  = (const float*)d_in[1];
  const float* W1 = (const float*)d_in[2];
  const float* b1 = (const float*)d_in[3];
  const float* Wa = (const float*)d_in[4];
  const float* ba = (const float*)d_in[5];
  const float* Wb = (const float*)d_in[6];
  const float* bb = (const float*)d_in[7];
  const float* W2 = (const float*)d_in[8];
  const float* b2 = (const float*)d_in[9];
  const float* W3 = (const float*)d_in[10];
  const float* b3 = (const float*)d_in[11];

  float* recon  = (float*)d_out;
  float* oalpha = recon + (size_t)BATCH * NDIM;
  float* obeta  = oalpha + (size_t)BATCH * LAT;

  // ws layout (16B-aligned offsets), total 37,945,856 B
  char* ws = (char*)d_ws;
  bf16_t* h   = (bf16_t*)(ws);                 // 16,777,216
  bf16_t* h2  = (bf16_t*)(ws + 16777216);      // 16,777,216
  bf16_t* pi  = (bf16_t*)(ws + 33554432);      //  2,097,152
  bf16_t* w1  = (bf16_t*)(ws + 35651584);      //  1,048,576
  bf16_t* w3  = (bf16_t*)(ws + 36700160);      //  1,048,576
  bf16_t* wab = (bf16_t*)(ws + 37748736);      //    131,072
  bf16_t* w2p = (bf16_t*)(ws + 37879808);      //     65,536
  float*  bab = (float*)(ws + 37945344);       //        512

  prep_w_kernel<<<512, 256, 0, stream>>>(W1, W3, Wa, Wb, W2, ba, bb,
                                         w1, w3, wab, w2p, bab);
  // h = relu(x @ W1^T + b1); MT=128, 8-wave, dbuf, A=x f32 reg-staged (T14)
  gemm_kernel<1, 0, 128, 1><<<512, 512, 0, stream>>>(
      x, w1, b1, (void*)h, nullptr, nullptr, BATCH, HID, NDIM);
  // alpha/beta = softplus(h @ Wab^T + bab)+1e-4 -> d_out  (MT=64, 8-wave)
  gemm_kernel<0, 2, 64, 1><<<256, 512, 0, stream>>>(
      h, wab, bab, nullptr, oalpha, obeta, BATCH, 128, HID);
  // pi (stick-breaking) -> ws, padded [16384,64] bf16
  stick_kernel<<<4096, 256, 0, stream>>>(u, oalpha, obeta, pi);
  // h2 = relu(pi @ W2p^T + b2)  (MT=64, K=64 -> nt=1, single-buffer)
  gemm_kernel<0, 0, 64, 0><<<1024, 512, 0, stream>>>(
      pi, w2p, b2, (void*)h2, nullptr, nullptr, BATCH, HID, 64);
  // recon = sigmoid(h2 @ W3^T + b3)  (MT=128, 8-wave, dbuf)
  gemm_kernel<0, 1, 128, 1><<<1024, 512, 0, stream>>>(
      h2, w3, b3, (void*)recon, nullptr, nullptr, BATCH, NDIM, HID);
}